// Round 8
// baseline (2654.428 us; speedup 1.0000x reference)
//
#include <hip/hip_runtime.h>
#include <hip/hip_bf16.h>
#include <stdint.h>

#define BATCH 4
#define NPTS 50000
#define MTOT (BATCH * NPTS)   // 200000 points
#define HID 256
#define NBLK 5
#define CDIM 128

typedef float  floatx4 __attribute__((ext_vector_type(4)));
typedef short  short8  __attribute__((ext_vector_type(8)));

// ---- workspace layout (bytes) ----
#define OFF_WCP   0u           // 5*4*16*512 bf16  = 327,680 B
#define OFF_W0P   327680u      // 5*8*16*512 bf16  = 655,360 B
#define OFF_W1P   983040u      // 655,360 B
#define OFF_GT    1638400u     // 4*32768*32 bf16  = 8,388,608 B
#define OFF_PT    10027008u    // 3*4*16384*32 bf16 = 12,582,912 B  (end 22,609,920)

__device__ __forceinline__ unsigned short f2bf(float f) {
  unsigned u = __builtin_bit_cast(unsigned, f);
  u += 0x7fffu + ((u >> 16) & 1u);
  return (unsigned short)(u >> 16);
}
__device__ __forceinline__ unsigned pack2bf(float a, float b) {
  return (unsigned)f2bf(a) | ((unsigned)f2bf(b) << 16);
}
// packed cvt: lowers to v_cvt_pk_bf16_f32 on gfx950; RNE, value-identical to f2bf
__device__ __forceinline__ unsigned pk2(float a, float b) {
  __hip_bfloat162 t = __float22bfloat162_rn(make_float2(a, b));
  unsigned u; __builtin_memcpy(&u, &t, sizeof(u));
  return u;
}

// ---------------- prep: weight prepack + feature transpose (one launch) ----------------
// pack: fp32 row-major (K x 256) -> bf16 16x16x32 A-fragment-major.
// Fragment tile (ks, fm): 512 bf16, entry [l*8+j] = W[ks*32 + (l>>4)*8 + j][fm*16 + (l&15)]
__global__ void prep(const float* __restrict__ Wc, const float* __restrict__ W0,
                     const float* __restrict__ W1,
                     const float* __restrict__ g, const float* __restrict__ xy,
                     const float* __restrict__ yz, const float* __restrict__ xz,
                     unsigned short* __restrict__ wcp, unsigned short* __restrict__ w0p,
                     unsigned short* __restrict__ w1p,
                     unsigned short* __restrict__ gt, unsigned short* __restrict__ pt) {
  const int bid = blockIdx.x;
  if (bid < 3200) {
    int e = bid * 256 + threadIdx.x;
    const int WC_E = NBLK * 32768;   // 163840
    const int W_E  = NBLK * 65536;   // 327680
    const float* src;
    unsigned short* dst;
    int idx, per;
    if (e < WC_E)            { src = Wc; dst = wcp; idx = e;              per = 32768; }
    else if (e < WC_E + W_E) { src = W0; dst = w0p; idx = e - WC_E;       per = 65536; }
    else                     { src = W1; dst = w1p; idx = e - WC_E - W_E; per = 65536; }
    int blk = idx / per, r = idx % per;
    int j = r & 7, l = (r >> 3) & 63, tile = r >> 9;
    int fm = tile & 15, ks = tile >> 4;
    int k = ks * 32 + (l >> 4) * 8 + j;
    int n = fm * 16 + (l & 15);
    dst[idx] = f2bf(src[(size_t)blk * per + (size_t)k * 256 + n]);
    return;
  }
  // feature transpose to channel-last bf16
  int tid = (bid - 3200) * 256 + threadIdx.x;
  float v[32];
  unsigned short* dst;
  if (tid < BATCH * 32768) {                 // grid: (B,32,32768) -> (B,32768,32)
    int b = tid >> 15, sp = tid & 32767;
    const float* src = g + ((size_t)b * 32) * 32768 + sp;
#pragma unroll
    for (int c = 0; c < 32; c++) v[c] = src[(size_t)c * 32768];
    dst = gt + (size_t)tid * 32;
  } else {                                   // planes: (3,B,32,16384) -> (3,B,16384,32)
    int t2 = tid - BATCH * 32768;
    int pl = t2 >> 16, rem = t2 & 65535;
    int b = rem >> 14, hw = rem & 16383;
    const float* pp = (pl == 0) ? xy : ((pl == 1) ? yz : xz);
    const float* src = pp + ((size_t)b * 32) * 16384 + hw;
#pragma unroll
    for (int c = 0; c < 32; c++) v[c] = src[(size_t)c * 16384];
    dst = pt + (size_t)t2 * 32;
  }
  uint4* d4 = (uint4*)dst;
#pragma unroll
  for (int i = 0; i < 4; i++) {
    uint4 u;
    u.x = pack2bf(v[i*8+0], v[i*8+1]);
    u.y = pack2bf(v[i*8+2], v[i*8+3]);
    u.z = pack2bf(v[i*8+4], v[i*8+5]);
    u.w = pack2bf(v[i*8+6], v[i*8+7]);
    d4[i] = u;
  }
}

// ---------------- 8-channel interpolation helpers (same math/order as before) ----------
__device__ __forceinline__ void acc8(float* a, const unsigned short* s, float wgt) {
  uint4 u = *(const uint4*)s;
  a[0] += wgt * __builtin_bit_cast(float, u.x << 16);
  a[1] += wgt * __builtin_bit_cast(float, u.x & 0xffff0000u);
  a[2] += wgt * __builtin_bit_cast(float, u.y << 16);
  a[3] += wgt * __builtin_bit_cast(float, u.y & 0xffff0000u);
  a[4] += wgt * __builtin_bit_cast(float, u.z << 16);
  a[5] += wgt * __builtin_bit_cast(float, u.z & 0xffff0000u);
  a[6] += wgt * __builtin_bit_cast(float, u.w << 16);
  a[7] += wgt * __builtin_bit_cast(float, u.w & 0xffff0000u);
}
__device__ __forceinline__ short8 pack8(const float* a) {
  int4 bi;
  bi.x = (int)pk2(a[0], a[1]);
  bi.y = (int)pk2(a[2], a[3]);
  bi.z = (int)pk2(a[4], a[5]);
  bi.w = (int)pk2(a[6], a[7]);
  return __builtin_bit_cast(short8, bi);
}

// ---------------- barrier-free point-split MLP ----------------
// Block: 256 threads = 4 waves, 64 points. Wave w owns points [ptile+w*16, +16),
// ALL 256 hidden (16 fm-tiles of 16). Activation transpose C-layout -> B-layout goes
// through WAVE-PRIVATE LDS (same-wave ds_write -> ds_read, lgkmcnt-ordered):
// no __syncthreads anywhere. Fragment contents & accumulation order bit-identical
// to the R7 kernel (absmax-proven); only the final output dot is re-associated.
// net C-frag: hid = fm*16 + lq*4 + r ; pt = w*16 + lr (one pt per lane).
#define PT_DW 132   // dwords per point row (128 data + 4 pad); 132 % 32 = 4
#define H_DW  66    // dwords per point row, h half (64 data + 2 pad)

__global__ __launch_bounds__(256, 2) void mlp(
    const float* __restrict__ p, const float* __restrict__ Wp, const float* __restrict__ bp,
    const float* __restrict__ bc, const float* __restrict__ b0, const float* __restrict__ b1,
    const float* __restrict__ Wout, const float* __restrict__ bout,
    const unsigned short* __restrict__ wcp, const unsigned short* __restrict__ w0p,
    const unsigned short* __restrict__ w1p,
    const unsigned short* __restrict__ gt, const unsigned short* __restrict__ ptab,
    float* __restrict__ out) {
  __shared__ __align__(16) unsigned actn[4 * 16 * PT_DW];  // relu(net) pack, 33,792 B
  __shared__ __align__(16) unsigned acth[4 * 16 * H_DW];   // relu(h) half pack, 16,896 B
  const int tid = threadIdx.x;
  const int w = tid >> 6, l = tid & 63, lq = l >> 4, lr = l & 15;
  const int ptile = blockIdx.x * 64;
  const int m = ptile + w * 16 + lr;     // this lane's point
  const int b = m / NPTS;

  unsigned* an = actn + (size_t)(w * 16 + lr) * PT_DW;
  unsigned* ah = acth + (size_t)(w * 16 + lr) * H_DW;

  // ---- per-lane direct gather: 8 channels per source (lq picks the slice) ----
  float px = p[3*m], py = p[3*m+1], pz = p[3*m+2];
  const float inv = 1.0f / 1.101f;       // 1/(1+PAD+1e-3)
  float ux = fminf(fmaxf(px * inv + 0.5f, 0.0f), 1.0f - 1e-5f);
  float uy = fminf(fmaxf(py * inv + 0.5f, 0.0f), 1.0f - 1e-5f);
  float uz = fminf(fmaxf(pz * inv + 0.5f, 0.0f), 1.0f - 1e-5f);
  short8 cfB[4];
  {
    float a8[8];
    // grid (trilinear, res 32, x->W fastest)
#pragma unroll
    for (int c = 0; c < 8; c++) a8[c] = 0.f;
    {
      float fx = ux * 31.f, fy = uy * 31.f, fz = uz * 31.f;
      int x0 = (int)fx, y0 = (int)fy, z0 = (int)fz;
      float wx = fx - x0, wy = fy - y0, wz = fz - z0;
      int x1 = min(x0 + 1, 31), y1 = min(y0 + 1, 31), z1 = min(z0 + 1, 31);
      const unsigned short* gb = gt + ((size_t)b * 32768) * 32 + lq * 8;
      #define GI(z,y,x) (((size_t)(((z)*32 + (y))*32 + (x))) * 32)
      acc8(a8, gb + GI(z0,y0,x0), (1-wx)*(1-wy)*(1-wz));
      acc8(a8, gb + GI(z0,y0,x1), wx*(1-wy)*(1-wz));
      acc8(a8, gb + GI(z0,y1,x0), (1-wx)*wy*(1-wz));
      acc8(a8, gb + GI(z0,y1,x1), wx*wy*(1-wz));
      acc8(a8, gb + GI(z1,y0,x0), (1-wx)*(1-wy)*wz);
      acc8(a8, gb + GI(z1,y0,x1), wx*(1-wy)*wz);
      acc8(a8, gb + GI(z1,y1,x0), (1-wx)*wy*wz);
      acc8(a8, gb + GI(z1,y1,x1), wx*wy*wz);
    }
    cfB[0] = pack8(a8);
    // planes (bilinear, res 128): xy(u=x,v=y), yz(u=y,v=z), xz(u=x,v=z)
#pragma unroll
    for (int pl = 0; pl < 3; pl++) {
#pragma unroll
      for (int c = 0; c < 8; c++) a8[c] = 0.f;
      float uu = (pl == 1) ? uy : ux;
      float vv = (pl == 0) ? uy : uz;
      float fx = uu * 127.f, fy = vv * 127.f;
      int x0 = (int)fx, y0 = (int)fy;
      float wx = fx - x0, wy = fy - y0;
      int x1 = min(x0 + 1, 127), y1 = min(y0 + 1, 127);
      const unsigned short* pb = ptab + ((size_t)(pl * BATCH + b) * 16384) * 32 + lq * 8;
      acc8(a8, pb + (size_t)(y0*128 + x0) * 32, (1-wx)*(1-wy));
      acc8(a8, pb + (size_t)(y0*128 + x1) * 32, wx*(1-wy));
      acc8(a8, pb + (size_t)(y1*128 + x0) * 32, (1-wx)*wy);
      acc8(a8, pb + (size_t)(y1*128 + x1) * 32, wx*wy);
      cfB[pl + 1] = pack8(a8);
    }
  }

  // ---- init: net = p @ Wp + bp ----
  floatx4 net[16];   // [fm]: hid = fm*16 + lq*4 + r, pt = w*16+lr
#pragma unroll
  for (int fm = 0; fm < 16; fm++) {
    int h4 = fm*4 + lq;
    float4 w0q = ((const float4*)Wp)[h4];
    float4 w1q = ((const float4*)(Wp + 256))[h4];
    float4 w2q = ((const float4*)(Wp + 512))[h4];
    float4 bq  = ((const float4*)bp)[h4];
    net[fm][0] = bq.x + px*w0q.x + py*w1q.x + pz*w2q.x;
    net[fm][1] = bq.y + px*w0q.y + py*w1q.y + pz*w2q.y;
    net[fm][2] = bq.z + px*w0q.z + py*w1q.z + pz*w2q.z;
    net[fm][3] = bq.w + px*w0q.w + py*w1q.w + pz*w2q.w;
  }

  for (int i = 0; i < NBLK; i++) {
    // ---- S1: net += Wc^T . c^T  (K = 128, B-frags in registers) ----
    const unsigned short* wcb = wcp + i * 32768;
#pragma unroll
    for (int ks = 0; ks < 4; ks++)
#pragma unroll
      for (int fm = 0; fm < 16; fm++) {
        short8 af = *(const short8*)(wcb + (size_t)(ks*16 + fm) * 512 + l*8);
        net[fm] = __builtin_amdgcn_mfma_f32_16x16x32_bf16(af, cfB[ks], net[fm], 0, 0, 0);
      }
    // ---- + bc, pack relu(net) -> wave-private LDS ----
#pragma unroll
    for (int fm = 0; fm < 16; fm++) {
      float4 bq = ((const float4*)(bc + i*256))[fm*4 + lq];
      net[fm][0] += bq.x; net[fm][1] += bq.y; net[fm][2] += bq.z; net[fm][3] += bq.w;
      uint2 uu;
      uu.x = pk2(fmaxf(net[fm][0],0.f), fmaxf(net[fm][1],0.f));
      uu.y = pk2(fmaxf(net[fm][2],0.f), fmaxf(net[fm][3],0.f));
      *(uint2*)(an + fm*8 + lq*2) = uu;    // dwords (fm*16+lq*4)/2
    }
    // ---- S2 (fmh halves) + S3 (matching K-quarter) ----
    const unsigned short* w0b = w0p + i * 65536;
    const unsigned short* w1b = w1p + i * 65536;
#pragma unroll
    for (int fmh = 0; fmh < 2; fmh++) {
      floatx4 h[8];
#pragma unroll
      for (int fm2 = 0; fm2 < 8; fm2++) h[fm2] = (floatx4){0.f,0.f,0.f,0.f};
#pragma unroll
      for (int ks = 0; ks < 8; ks++) {
        short8 bf = *(const short8*)(an + ks*16 + lq*4);   // own pt row, k=ks*32+lq*8..
#pragma unroll
        for (int fm2 = 0; fm2 < 8; fm2++) {
          short8 af = *(const short8*)(w0b + (size_t)(ks*16 + fmh*8 + fm2) * 512 + l*8);
          h[fm2] = __builtin_amdgcn_mfma_f32_16x16x32_bf16(af, bf, h[fm2], 0, 0, 0);
        }
      }
      // + b0, pack relu(h) half -> wave-private LDS
#pragma unroll
      for (int fm2 = 0; fm2 < 8; fm2++) {
        float4 bq = ((const float4*)(b0 + i*256))[fmh*32 + fm2*4 + lq];
        uint2 uu;
        uu.x = pk2(fmaxf(h[fm2][0]+bq.x,0.f), fmaxf(h[fm2][1]+bq.y,0.f));
        uu.y = pk2(fmaxf(h[fm2][2]+bq.z,0.f), fmaxf(h[fm2][3]+bq.w,0.f));
        *(uint2*)(ah + fm2*8 + lq*2) = uu;
      }
      // S3 K-quarter: net += W1[k half] . relu(h half)
#pragma unroll
      for (int ksl = 0; ksl < 4; ksl++) {
        short8 bf = *(const short8*)(ah + ksl*16 + lq*4);
#pragma unroll
        for (int fm = 0; fm < 16; fm++) {
          short8 af = *(const short8*)(w1b + (size_t)((fmh*4 + ksl)*16 + fm) * 512 + l*8);
          net[fm] = __builtin_amdgcn_mfma_f32_16x16x32_bf16(af, bf, net[fm], 0, 0, 0);
        }
      }
    }
    // ---- + b1 ----
#pragma unroll
    for (int fm = 0; fm < 16; fm++) {
      float4 bq = ((const float4*)(b1 + i*256))[fm*4 + lq];
      net[fm][0] += bq.x; net[fm][1] += bq.y; net[fm][2] += bq.z; net[fm][3] += bq.w;
    }
  }

  // ---- out = relu(net) @ Wout + bout (per-wave, no atomics) ----
  float s = 0.f;
#pragma unroll
  for (int fm = 0; fm < 16; fm++) {
    float4 wq = ((const float4*)Wout)[fm*4 + lq];
    s += fmaxf(net[fm][0],0.f)*wq.x + fmaxf(net[fm][1],0.f)*wq.y
       + fmaxf(net[fm][2],0.f)*wq.z + fmaxf(net[fm][3],0.f)*wq.w;
  }
  s += __shfl_xor(s, 16, 64);
  s += __shfl_xor(s, 32, 64);
  if (lq == 0) out[m] = s + bout[0];
}

extern "C" void kernel_launch(void* const* d_in, const int* in_sizes, int n_in,
                              void* d_out, int out_size, void* d_ws, size_t ws_size,
                              hipStream_t stream) {
  const float* p      = (const float*)d_in[0];
  const float* c_grid = (const float*)d_in[1];
  const float* c_xy   = (const float*)d_in[2];
  const float* c_yz   = (const float*)d_in[3];
  const float* c_xz   = (const float*)d_in[4];
  const float* Wp     = (const float*)d_in[5];
  const float* bp     = (const float*)d_in[6];
  const float* Wc     = (const float*)d_in[7];
  const float* bc     = (const float*)d_in[8];
  const float* W0     = (const float*)d_in[9];
  const float* b0     = (const float*)d_in[10];
  const float* W1     = (const float*)d_in[11];
  const float* b1     = (const float*)d_in[12];
  const float* Wout   = (const float*)d_in[13];
  const float* bout   = (const float*)d_in[14];

  char* ws = (char*)d_ws;
  unsigned short* wcp = (unsigned short*)(ws + OFF_WCP);
  unsigned short* w0p = (unsigned short*)(ws + OFF_W0P);
  unsigned short* w1p = (unsigned short*)(ws + OFF_W1P);
  unsigned short* gt  = (unsigned short*)(ws + OFF_GT);
  unsigned short* pt  = (unsigned short*)(ws + OFF_PT);
  float* out = (float*)d_out;

  prep<<<4480, 256, 0, stream>>>(Wc, W0, W1, c_grid, c_xy, c_yz, c_xz,
                                 wcp, w0p, w1p, gt, pt);
  mlp<<<MTOT / 64, 256, 0, stream>>>(p, Wp, bp, bc, b0, b1, Wout, bout,
                                     wcp, w0p, w1p, gt, pt, out);
}

// Round 10
// 757.367 us; speedup vs baseline: 3.5048x; 3.5048x over previous
//
#include <hip/hip_runtime.h>
#include <hip/hip_bf16.h>
#include <stdint.h>

#define BATCH 4
#define NPTS 50000
#define MTOT (BATCH * NPTS)   // 200000 points
#define HID 256
#define NBLK 5
#define CDIM 128

typedef float  floatx4 __attribute__((ext_vector_type(4)));
typedef short  short8  __attribute__((ext_vector_type(8)));

// ---- workspace layout (bytes) ----
#define OFF_WCP   0u           // 5*4*16*512 bf16  = 327,680 B
#define OFF_W0P   327680u      // 5*8*16*512 bf16  = 655,360 B
#define OFF_W1P   983040u      // 655,360 B
#define OFF_GT    1638400u     // 4*32768*32 bf16  = 8,388,608 B
#define OFF_PT    10027008u    // 3*4*16384*32 bf16 = 12,582,912 B  (end 22,609,920)

__device__ __forceinline__ unsigned short f2bf(float f) {
  unsigned u = __builtin_bit_cast(unsigned, f);
  u += 0x7fffu + ((u >> 16) & 1u);
  return (unsigned short)(u >> 16);
}
__device__ __forceinline__ unsigned pack2bf(float a, float b) {
  return (unsigned)f2bf(a) | ((unsigned)f2bf(b) << 16);
}
// packed cvt: lowers to v_cvt_pk_bf16_f32 on gfx950; RNE, value-identical to f2bf
__device__ __forceinline__ unsigned pk2(float a, float b) {
  __hip_bfloat162 t = __float22bfloat162_rn(make_float2(a, b));
  unsigned u; __builtin_memcpy(&u, &t, sizeof(u));
  return u;
}

// ---------------- prep: weight prepack + feature transpose (one launch) ----------------
__global__ void prep(const float* __restrict__ Wc, const float* __restrict__ W0,
                     const float* __restrict__ W1,
                     const float* __restrict__ g, const float* __restrict__ xy,
                     const float* __restrict__ yz, const float* __restrict__ xz,
                     unsigned short* __restrict__ wcp, unsigned short* __restrict__ w0p,
                     unsigned short* __restrict__ w1p,
                     unsigned short* __restrict__ gt, unsigned short* __restrict__ pt) {
  const int bid = blockIdx.x;
  if (bid < 3200) {
    int e = bid * 256 + threadIdx.x;
    const int WC_E = NBLK * 32768;   // 163840
    const int W_E  = NBLK * 65536;   // 327680
    const float* src;
    unsigned short* dst;
    int idx, per;
    if (e < WC_E)            { src = Wc; dst = wcp; idx = e;              per = 32768; }
    else if (e < WC_E + W_E) { src = W0; dst = w0p; idx = e - WC_E;       per = 65536; }
    else                     { src = W1; dst = w1p; idx = e - WC_E - W_E; per = 65536; }
    int blk = idx / per, r = idx % per;
    int j = r & 7, l = (r >> 3) & 63, tile = r >> 9;
    int fm = tile & 15, ks = tile >> 4;
    int k = ks * 32 + (l >> 4) * 8 + j;
    int n = fm * 16 + (l & 15);
    dst[idx] = f2bf(src[(size_t)blk * per + (size_t)k * 256 + n]);
    return;
  }
  int tid = (bid - 3200) * 256 + threadIdx.x;
  float v[32];
  unsigned short* dst;
  if (tid < BATCH * 32768) {                 // grid: (B,32,32768) -> (B,32768,32)
    int b = tid >> 15, sp = tid & 32767;
    const float* src = g + ((size_t)b * 32) * 32768 + sp;
#pragma unroll
    for (int c = 0; c < 32; c++) v[c] = src[(size_t)c * 32768];
    dst = gt + (size_t)tid * 32;
  } else {                                   // planes: (3,B,32,16384) -> (3,B,16384,32)
    int t2 = tid - BATCH * 32768;
    int pl = t2 >> 16, rem = t2 & 65535;
    int b = rem >> 14, hw = rem & 16383;
    const float* pp = (pl == 0) ? xy : ((pl == 1) ? yz : xz);
    const float* src = pp + ((size_t)b * 32) * 16384 + hw;
#pragma unroll
    for (int c = 0; c < 32; c++) v[c] = src[(size_t)c * 16384];
    dst = pt + (size_t)t2 * 32;
  }
  uint4* d4 = (uint4*)dst;
#pragma unroll
  for (int i = 0; i < 4; i++) {
    uint4 u;
    u.x = pack2bf(v[i*8+0], v[i*8+1]);
    u.y = pack2bf(v[i*8+2], v[i*8+3]);
    u.z = pack2bf(v[i*8+4], v[i*8+5]);
    u.w = pack2bf(v[i*8+6], v[i*8+7]);
    d4[i] = u;
  }
}

// ---------------- interpolation helpers (bit-identical to the R3 features kernel) ----------
__device__ __forceinline__ void acc32(float* acc, const unsigned short* s, float w) {
  const uint4* q = (const uint4*)s;
#pragma unroll
  for (int i = 0; i < 4; i++) {
    uint4 u = q[i];
    acc[i*8+0] += w * __builtin_bit_cast(float, u.x << 16);
    acc[i*8+1] += w * __builtin_bit_cast(float, u.x & 0xffff0000u);
    acc[i*8+2] += w * __builtin_bit_cast(float, u.y << 16);
    acc[i*8+3] += w * __builtin_bit_cast(float, u.y & 0xffff0000u);
    acc[i*8+4] += w * __builtin_bit_cast(float, u.z << 16);
    acc[i*8+5] += w * __builtin_bit_cast(float, u.z & 0xffff0000u);
    acc[i*8+6] += w * __builtin_bit_cast(float, u.w << 16);
    acc[i*8+7] += w * __builtin_bit_cast(float, u.w & 0xffff0000u);
  }
}
__device__ __forceinline__ void store32_lds(unsigned short* dst, const float* a) {
#pragma unroll
  for (int i = 0; i < 4; i++) {
    uint4 u;
    u.x = pack2bf(a[i*8+0], a[i*8+1]);
    u.y = pack2bf(a[i*8+2], a[i*8+3]);
    u.z = pack2bf(a[i*8+4], a[i*8+5]);
    u.w = pack2bf(a[i*8+6], a[i*8+7]);
    *(uint4*)(dst + i * 8) = u;
  }
}

// ---------------- fused gather + MLP: single act buffer, 3 blocks/CU ----------------
// Workgroup: 64 points, 4 waves; wave w owns hidden rows [w*64, w*64+64).
// LDS: act 33.8 KB (shared relu buffer) + cf 17.4 KB (read-only features) = 51.5 KB
// -> 3 blocks/CU. Registers budgeted <=170/lane (3 waves/SIMD): cf lives in LDS
// (not 64 VGPRs), S2 runs in 4 hid-quarters (h transient 16 regs, stash 32).
// Per-output-tile K-accumulation order identical to R7 -> absmax 0.03143311.
#define ACT_STRIDE 264   // 132 dw % 32 = 4 -> uniform free 2-way banking
#define CF_STRIDE  136   // 68 dw % 32 = 4  -> same pattern

__global__ __launch_bounds__(256, 3) void mlp(
    const float* __restrict__ p, const float* __restrict__ Wp, const float* __restrict__ bp,
    const float* __restrict__ bc, const float* __restrict__ b0, const float* __restrict__ b1,
    const float* __restrict__ Wout, const float* __restrict__ bout,
    const unsigned short* __restrict__ wcp, const unsigned short* __restrict__ w0p,
    const unsigned short* __restrict__ w1p,
    const unsigned short* __restrict__ gt, const unsigned short* __restrict__ ptab,
    float* __restrict__ out) {
  __shared__ __align__(16) unsigned short act[64 * ACT_STRIDE];  // 33,792 B
  __shared__ __align__(16) unsigned short cfb[64 * CF_STRIDE];   // 17,408 B
  __shared__ float obuf[64];
  const int tid = threadIdx.x;
  const int w = tid >> 6, l = tid & 63, lq = l >> 4, lr = l & 15;
  const int ptile = blockIdx.x * 64;

  // ---- gather prologue: 4 threads per point, one feature source each -> cfb ----
  {
    int pl   = tid & 3;        // 0: grid, 1: xy, 2: yz, 3: xz
    int mloc = tid >> 2;       // 0..63
    int m = ptile + mloc;
    int b = m / NPTS;
    float px = p[3*m], py = p[3*m+1], pz = p[3*m+2];
    const float inv = 1.0f / 1.101f;       // 1/(1+PAD+1e-3)
    float ux = fminf(fmaxf(px * inv + 0.5f, 0.0f), 1.0f - 1e-5f);
    float uy = fminf(fmaxf(py * inv + 0.5f, 0.0f), 1.0f - 1e-5f);
    float uz = fminf(fmaxf(pz * inv + 0.5f, 0.0f), 1.0f - 1e-5f);
    float acc[32];
#pragma unroll
    for (int c = 0; c < 32; c++) acc[c] = 0.f;
    if (pl == 0) {
      float fx = ux * 31.f, fy = uy * 31.f, fz = uz * 31.f;
      int x0 = (int)fx, y0 = (int)fy, z0 = (int)fz;
      float wx = fx - x0, wy = fy - y0, wz = fz - z0;
      int x1 = min(x0 + 1, 31), y1 = min(y0 + 1, 31), z1 = min(z0 + 1, 31);
      const unsigned short* gb = gt + ((size_t)b * 32768) * 32;
      #define GI(z,y,x) (((size_t)(((z)*32 + (y))*32 + (x))) * 32)
      acc32(acc, gb + GI(z0,y0,x0), (1-wx)*(1-wy)*(1-wz));
      acc32(acc, gb + GI(z0,y0,x1), wx*(1-wy)*(1-wz));
      acc32(acc, gb + GI(z0,y1,x0), (1-wx)*wy*(1-wz));
      acc32(acc, gb + GI(z0,y1,x1), wx*wy*(1-wz));
      acc32(acc, gb + GI(z1,y0,x0), (1-wx)*(1-wy)*wz);
      acc32(acc, gb + GI(z1,y0,x1), wx*(1-wy)*wz);
      acc32(acc, gb + GI(z1,y1,x0), (1-wx)*wy*wz);
      acc32(acc, gb + GI(z1,y1,x1), wx*wy*wz);
    } else {
      float uu = (pl == 2) ? uy : ux;
      float vv = (pl == 1) ? uy : uz;
      float fx = uu * 127.f, fy = vv * 127.f;
      int x0 = (int)fx, y0 = (int)fy;
      float wx = fx - x0, wy = fy - y0;
      int x1 = min(x0 + 1, 127), y1 = min(y0 + 1, 127);
      const unsigned short* pb = ptab + ((size_t)((pl - 1) * BATCH + b) * 16384) * 32;
      acc32(acc, pb + ((size_t)(y0*128 + x0)) * 32, (1-wx)*(1-wy));
      acc32(acc, pb + ((size_t)(y0*128 + x1)) * 32, wx*(1-wy));
      acc32(acc, pb + ((size_t)(y1*128 + x0)) * 32, (1-wx)*wy);
      acc32(acc, pb + ((size_t)(y1*128 + x1)) * 32, wx*wy);
    }
    store32_lds(&cfb[(size_t)mloc * CF_STRIDE + pl * 32], acc);
  }

  floatx4 net[4][4];   // [fm][fn]; hidden = w*64 + fm*16 + lq*4 + r ; point = fn*16 + lr

  // ---- init: net = p @ Wp + bp ----
  float pv[4][3];
#pragma unroll
  for (int fn = 0; fn < 4; fn++) {
    int pg = ptile + fn * 16 + lr;
    pv[fn][0] = p[pg*3]; pv[fn][1] = p[pg*3+1]; pv[fn][2] = p[pg*3+2];
  }
#pragma unroll
  for (int fm = 0; fm < 4; fm++) {
    int h4 = w*16 + fm*4 + lq;
    float4 w0q = ((const float4*)Wp)[h4];
    float4 w1q = ((const float4*)(Wp + 256))[h4];
    float4 w2q = ((const float4*)(Wp + 512))[h4];
    float4 bq  = ((const float4*)bp)[h4];
    float wq[4][3] = {{w0q.x,w1q.x,w2q.x},{w0q.y,w1q.y,w2q.y},
                      {w0q.z,w1q.z,w2q.z},{w0q.w,w1q.w,w2q.w}};
    float bb[4] = {bq.x, bq.y, bq.z, bq.w};
#pragma unroll
    for (int r = 0; r < 4; r++)
#pragma unroll
      for (int fn = 0; fn < 4; fn++)
        net[fm][fn][r] = bb[r] + pv[fn][0]*wq[r][0] + pv[fn][1]*wq[r][1] + pv[fn][2]*wq[r][2];
  }
  __syncthreads();   // cfb complete (read-only from here on)

  for (int i = 0; i < NBLK; i++) {
    const unsigned short* wcb = wcp + i * 32768;
    const unsigned short* w0b = w0p + i * 65536;
    const unsigned short* w1b = w1p + i * 65536;
    // ---- S1: net += Wc^T . c^T  (K = 128, B-frags from read-only cfb) ----
#pragma unroll
    for (int ks = 0; ks < 4; ks++) {
      short8 af[4], bf[4];
#pragma unroll
      for (int fm = 0; fm < 4; fm++)
        af[fm] = *(const short8*)(wcb + (size_t)(ks*16 + w*4 + fm) * 512 + l*8);
#pragma unroll
      for (int fn = 0; fn < 4; fn++)
        bf[fn] = *(const short8*)(&cfb[(size_t)(fn*16 + lr) * CF_STRIDE + ks*32 + lq*8]);
#pragma unroll
      for (int fm = 0; fm < 4; fm++)
#pragma unroll
        for (int fn = 0; fn < 4; fn++)
          net[fm][fn] = __builtin_amdgcn_mfma_f32_16x16x32_bf16(af[fm], bf[fn], net[fm][fn], 0, 0, 0);
    }
    // ---- + bc (in regs) ----
#pragma unroll
    for (int fm = 0; fm < 4; fm++) {
      float4 bq = ((const float4*)(bc + i*256))[w*16 + fm*4 + lq];
#pragma unroll
      for (int fn = 0; fn < 4; fn++) {
        net[fm][fn][0] += bq.x; net[fm][fn][1] += bq.y;
        net[fm][fn][2] += bq.z; net[fm][fn][3] += bq.w;
      }
    }
    __syncthreads();   // B0: previous iteration's S3 reads of act are done
    // ---- write relu(net) -> act ----
#pragma unroll
    for (int fm = 0; fm < 4; fm++)
#pragma unroll
      for (int fn = 0; fn < 4; fn++) {
        uint2 uu;
        uu.x = pk2(fmaxf(net[fm][fn][0],0.f), fmaxf(net[fm][fn][1],0.f));
        uu.y = pk2(fmaxf(net[fm][fn][2],0.f), fmaxf(net[fm][fn][3],0.f));
        *(uint2*)(&act[(size_t)(fn*16 + lr) * ACT_STRIDE + w*64 + fm*16 + lq*4]) = uu;
      }
    __syncthreads();   // B1: act = relu(net) complete
    // ---- S2: h = W0^T . relu(net)^T  (K = 256), 4 hid-quarters; stash packed relu(h) ----
    uint2 st[4][4];    // [q][fn]
#pragma unroll
    for (int q = 0; q < 4; q++) {
      floatx4 h[4];
#pragma unroll
      for (int fn = 0; fn < 4; fn++) h[fn] = (floatx4){0.f,0.f,0.f,0.f};
#pragma unroll
      for (int ks = 0; ks < 8; ks++) {
        short8 af = *(const short8*)(w0b + (size_t)(ks*16 + w*4 + q) * 512 + l*8);
        short8 bf[4];
#pragma unroll
        for (int fn = 0; fn < 4; fn++)
          bf[fn] = *(const short8*)(&act[(size_t)(fn*16 + lr) * ACT_STRIDE + ks*32 + lq*8]);
#pragma unroll
        for (int fn = 0; fn < 4; fn++)
          h[fn] = __builtin_amdgcn_mfma_f32_16x16x32_bf16(af, bf[fn], h[fn], 0, 0, 0);
      }
      float4 bq = ((const float4*)(b0 + i*256))[w*16 + q*4 + lq];
#pragma unroll
      for (int fn = 0; fn < 4; fn++) {
        st[q][fn].x = pk2(fmaxf(h[fn][0]+bq.x,0.f), fmaxf(h[fn][1]+bq.y,0.f));
        st[q][fn].y = pk2(fmaxf(h[fn][2]+bq.z,0.f), fmaxf(h[fn][3]+bq.w,0.f));
      }
    }
    __syncthreads();   // B2: all S2 reads of act are done
    // ---- write relu(h) -> act ----
#pragma unroll
    for (int q = 0; q < 4; q++)
#pragma unroll
      for (int fn = 0; fn < 4; fn++)
        *(uint2*)(&act[(size_t)(fn*16 + lr) * ACT_STRIDE + w*64 + q*16 + lq*4]) = st[q][fn];
    __syncthreads();   // B3: act = relu(h) complete
    // ---- S3: net += W1^T . relu(h)^T + b1 ----
#pragma unroll
    for (int ks = 0; ks < 8; ks++) {
      short8 af[4], bf[4];
#pragma unroll
      for (int fm = 0; fm < 4; fm++)
        af[fm] = *(const short8*)(w1b + (size_t)(ks*16 + w*4 + fm) * 512 + l*8);
#pragma unroll
      for (int fn = 0; fn < 4; fn++)
        bf[fn] = *(const short8*)(&act[(size_t)(fn*16 + lr) * ACT_STRIDE + ks*32 + lq*8]);
#pragma unroll
      for (int fm = 0; fm < 4; fm++)
#pragma unroll
        for (int fn = 0; fn < 4; fn++)
          net[fm][fn] = __builtin_amdgcn_mfma_f32_16x16x32_bf16(af[fm], bf[fn], net[fm][fn], 0, 0, 0);
    }
#pragma unroll
    for (int fm = 0; fm < 4; fm++) {
      float4 bq = ((const float4*)(b1 + i*256))[w*16 + fm*4 + lq];
#pragma unroll
      for (int fn = 0; fn < 4; fn++) {
        net[fm][fn][0] += bq.x; net[fm][fn][1] += bq.y;
        net[fm][fn][2] += bq.z; net[fm][fn][3] += bq.w;
      }
    }
  }

  // ---- out = relu(net) @ Wout + bout ----
  float s[4] = {0.f, 0.f, 0.f, 0.f};
#pragma unroll
  for (int fm = 0; fm < 4; fm++) {
    float4 wq = ((const float4*)Wout)[w*16 + fm*4 + lq];
    float wv[4] = {wq.x, wq.y, wq.z, wq.w};
#pragma unroll
    for (int r = 0; r < 4; r++)
#pragma unroll
      for (int fn = 0; fn < 4; fn++) s[fn] += fmaxf(net[fm][fn][r], 0.f) * wv[r];
  }
#pragma unroll
  for (int fn = 0; fn < 4; fn++) {
    s[fn] += __shfl_xor(s[fn], 16);
    s[fn] += __shfl_xor(s[fn], 32);
  }
  if (tid < 64) obuf[tid] = 0.f;
  __syncthreads();
  if (lq == 0) {
#pragma unroll
    for (int fn = 0; fn < 4; fn++) atomicAdd(&obuf[fn*16 + lr], s[fn]);
  }
  __syncthreads();
  if (tid < 64) out[ptile + tid] = obuf[tid] + bout[0];
}

extern "C" void kernel_launch(void* const* d_in, const int* in_sizes, int n_in,
                              void* d_out, int out_size, void* d_ws, size_t ws_size,
                              hipStream_t stream) {
  const float* p      = (const float*)d_in[0];
  const float* c_grid = (const float*)d_in[1];
  const float* c_xy   = (const float*)d_in[2];
  const float* c_yz   = (const float*)d_in[3];
  const float* c_xz   = (const float*)d_in[4];
  const float* Wp     = (const float*)d_in[5];
  const float* bp     = (const float*)d_in[6];
  const float* Wc     = (const float*)d_in[7];
  const float* bc     = (const float*)d_in[8];
  const float* W0     = (const float*)d_in[9];
  const float* b0     = (const float*)d_in[10];
  const float* W1     = (const float*)d_in[11];
  const float* b1     = (const float*)d_in[12];
  const float* Wout   = (const float*)d_in[13];
  const float* bout   = (const float*)d_in[14];

  char* ws = (char*)d_ws;
  unsigned short* wcp = (unsigned short*)(ws + OFF_WCP);
  unsigned short* w0p = (unsigned short*)(ws + OFF_W0P);
  unsigned short* w1p = (unsigned short*)(ws + OFF_W1P);
  unsigned short* gt  = (unsigned short*)(ws + OFF_GT);
  unsigned short* pt  = (unsigned short*)(ws + OFF_PT);
  float* out = (float*)d_out;

  prep<<<4480, 256, 0, stream>>>(Wc, W0, W1, c_grid, c_xy, c_yz, c_xz,
                                 wcp, w0p, w1p, gt, pt);
  mlp<<<MTOT / 64, 256, 0, stream>>>(p, Wp, bp, bc, b0, b1, Wout, bout,
                                     wcp, w0p, w1p, gt, pt, out);
}

// Round 11
// 576.252 us; speedup vs baseline: 4.6064x; 1.3143x over previous
//
#include <hip/hip_runtime.h>
#include <hip/hip_bf16.h>
#include <stdint.h>

#define BATCH 4
#define NPTS 50000
#define MTOT (BATCH * NPTS)   // 200000 points
#define HID 256
#define NBLK 5
#define CDIM 128

typedef float  floatx4 __attribute__((ext_vector_type(4)));
typedef short  short8  __attribute__((ext_vector_type(8)));

// ---- workspace layout (bytes) ----
#define OFF_WCP   0u           // 5*4*16*512 bf16  = 327,680 B
#define OFF_W0P   327680u      // 5*8*16*512 bf16  = 655,360 B
#define OFF_W1P   983040u      // 655,360 B
#define OFF_GT    1638400u     // 4*32768*32 bf16  = 8,388,608 B
#define OFF_PT    10027008u    // 3*4*16384*32 bf16 = 12,582,912 B  (end 22,609,920)

__device__ __forceinline__ unsigned short f2bf(float f) {
  unsigned u = __builtin_bit_cast(unsigned, f);
  u += 0x7fffu + ((u >> 16) & 1u);
  return (unsigned short)(u >> 16);
}
__device__ __forceinline__ unsigned pack2bf(float a, float b) {
  return (unsigned)f2bf(a) | ((unsigned)f2bf(b) << 16);
}
// packed cvt: lowers to v_cvt_pk_bf16_f32 on gfx950; RNE, value-identical to f2bf
__device__ __forceinline__ unsigned pk2(float a, float b) {
  __hip_bfloat162 t = __float22bfloat162_rn(make_float2(a, b));
  unsigned u; __builtin_memcpy(&u, &t, sizeof(u));
  return u;
}

// ---------------- prep: weight prepack + feature transpose (one launch) ----------------
// pack: fp32 row-major (K x 256) -> bf16 16x16x32 A-fragment-major.
// Fragment tile (ks, fm): 512 bf16, entry [l*8+j] = W[ks*32 + (l>>4)*8 + j][fm*16 + (l&15)]
__global__ void prep(const float* __restrict__ Wc, const float* __restrict__ W0,
                     const float* __restrict__ W1,
                     const float* __restrict__ g, const float* __restrict__ xy,
                     const float* __restrict__ yz, const float* __restrict__ xz,
                     unsigned short* __restrict__ wcp, unsigned short* __restrict__ w0p,
                     unsigned short* __restrict__ w1p,
                     unsigned short* __restrict__ gt, unsigned short* __restrict__ pt) {
  const int bid = blockIdx.x;
  if (bid < 3200) {
    int e = bid * 256 + threadIdx.x;
    const int WC_E = NBLK * 32768;   // 163840
    const int W_E  = NBLK * 65536;   // 327680
    const float* src;
    unsigned short* dst;
    int idx, per;
    if (e < WC_E)            { src = Wc; dst = wcp; idx = e;              per = 32768; }
    else if (e < WC_E + W_E) { src = W0; dst = w0p; idx = e - WC_E;       per = 65536; }
    else                     { src = W1; dst = w1p; idx = e - WC_E - W_E; per = 65536; }
    int blk = idx / per, r = idx % per;
    int j = r & 7, l = (r >> 3) & 63, tile = r >> 9;
    int fm = tile & 15, ks = tile >> 4;
    int k = ks * 32 + (l >> 4) * 8 + j;
    int n = fm * 16 + (l & 15);
    dst[idx] = f2bf(src[(size_t)blk * per + (size_t)k * 256 + n]);
    return;
  }
  int tid = (bid - 3200) * 256 + threadIdx.x;
  float v[32];
  unsigned short* dst;
  if (tid < BATCH * 32768) {                 // grid: (B,32,32768) -> (B,32768,32)
    int b = tid >> 15, sp = tid & 32767;
    const float* src = g + ((size_t)b * 32) * 32768 + sp;
#pragma unroll
    for (int c = 0; c < 32; c++) v[c] = src[(size_t)c * 32768];
    dst = gt + (size_t)tid * 32;
  } else {                                   // planes: (3,B,32,16384) -> (3,B,16384,32)
    int t2 = tid - BATCH * 32768;
    int pl = t2 >> 16, rem = t2 & 65535;
    int b = rem >> 14, hw = rem & 16383;
    const float* pp = (pl == 0) ? xy : ((pl == 1) ? yz : xz);
    const float* src = pp + ((size_t)b * 32) * 16384 + hw;
#pragma unroll
    for (int c = 0; c < 32; c++) v[c] = src[(size_t)c * 16384];
    dst = pt + (size_t)t2 * 32;
  }
  uint4* d4 = (uint4*)dst;
#pragma unroll
  for (int i = 0; i < 4; i++) {
    uint4 u;
    u.x = pack2bf(v[i*8+0], v[i*8+1]);
    u.y = pack2bf(v[i*8+2], v[i*8+3]);
    u.z = pack2bf(v[i*8+4], v[i*8+5]);
    u.w = pack2bf(v[i*8+6], v[i*8+7]);
    d4[i] = u;
  }
}

// ---------------- interpolation helpers (bit-identical to the R3 features kernel) ----------
__device__ __forceinline__ void acc32(float* acc, const unsigned short* s, float w) {
  const uint4* q = (const uint4*)s;
#pragma unroll
  for (int i = 0; i < 4; i++) {
    uint4 u = q[i];
    acc[i*8+0] += w * __builtin_bit_cast(float, u.x << 16);
    acc[i*8+1] += w * __builtin_bit_cast(float, u.x & 0xffff0000u);
    acc[i*8+2] += w * __builtin_bit_cast(float, u.y << 16);
    acc[i*8+3] += w * __builtin_bit_cast(float, u.y & 0xffff0000u);
    acc[i*8+4] += w * __builtin_bit_cast(float, u.z << 16);
    acc[i*8+5] += w * __builtin_bit_cast(float, u.z & 0xffff0000u);
    acc[i*8+6] += w * __builtin_bit_cast(float, u.w << 16);
    acc[i*8+7] += w * __builtin_bit_cast(float, u.w & 0xffff0000u);
  }
}
__device__ __forceinline__ void store32_lds(unsigned short* dst, const float* a) {
#pragma unroll
  for (int i = 0; i < 4; i++) {
    uint4 u;
    u.x = pack2bf(a[i*8+0], a[i*8+1]);
    u.y = pack2bf(a[i*8+2], a[i*8+3]);
    u.z = pack2bf(a[i*8+4], a[i*8+5]);
    u.w = pack2bf(a[i*8+6], a[i*8+7]);
    *(uint4*)(dst + i * 8) = u;
  }
}

// ---------------- fused gather + MLP (R7: measured 576 us total, no spill) ----------------
// Workgroup: 64 points, 256 threads = 4 waves; wave w owns hidden rows [w*64, w*64+64).
// K-loop = 2-buffer / 2-barrier structure; cf B-fragments hoisted to 64 persistent
// VGPRs per lane (S1 needs no memory reads for B). 2 waves/SIMD is this live set's
// natural occupancy — forcing 3 spills (measured R6/R10).
#define ACT_STRIDE 264   // 132 dw % 32 = 4 -> uniform free 2-way banking
#define CF_STRIDE  136   // 68 dw % 32 = 4  -> same pattern (staging only)

__global__ __launch_bounds__(256, 2) void mlp(
    const float* __restrict__ p, const float* __restrict__ Wp, const float* __restrict__ bp,
    const float* __restrict__ bc, const float* __restrict__ b0, const float* __restrict__ b1,
    const float* __restrict__ Wout, const float* __restrict__ bout,
    const unsigned short* __restrict__ wcp, const unsigned short* __restrict__ w0p,
    const unsigned short* __restrict__ w1p,
    const unsigned short* __restrict__ gt, const unsigned short* __restrict__ ptab,
    float* __restrict__ out) {
  __shared__ __align__(16) unsigned short act [64 * ACT_STRIDE];
  __shared__ __align__(16) unsigned short act2[64 * ACT_STRIDE];
  __shared__ float obuf[64];
  const int tid = threadIdx.x;
  const int w = tid >> 6, l = tid & 63, lq = l >> 4, lr = l & 15;
  const int ptile = blockIdx.x * 64;

  // ---- gather prologue: 4 threads per point, one feature source each; stage into act ----
  {
    int pl   = tid & 3;        // 0: grid, 1: xy, 2: yz, 3: xz
    int mloc = tid >> 2;       // 0..63
    int m = ptile + mloc;
    int b = m / NPTS;
    float px = p[3*m], py = p[3*m+1], pz = p[3*m+2];
    const float inv = 1.0f / 1.101f;       // 1/(1+PAD+1e-3)
    float ux = fminf(fmaxf(px * inv + 0.5f, 0.0f), 1.0f - 1e-5f);
    float uy = fminf(fmaxf(py * inv + 0.5f, 0.0f), 1.0f - 1e-5f);
    float uz = fminf(fmaxf(pz * inv + 0.5f, 0.0f), 1.0f - 1e-5f);
    float acc[32];
#pragma unroll
    for (int c = 0; c < 32; c++) acc[c] = 0.f;
    if (pl == 0) {
      float fx = ux * 31.f, fy = uy * 31.f, fz = uz * 31.f;
      int x0 = (int)fx, y0 = (int)fy, z0 = (int)fz;
      float wx = fx - x0, wy = fy - y0, wz = fz - z0;
      int x1 = min(x0 + 1, 31), y1 = min(y0 + 1, 31), z1 = min(z0 + 1, 31);
      const unsigned short* gb = gt + ((size_t)b * 32768) * 32;
      #define GI(z,y,x) (((size_t)(((z)*32 + (y))*32 + (x))) * 32)
      acc32(acc, gb + GI(z0,y0,x0), (1-wx)*(1-wy)*(1-wz));
      acc32(acc, gb + GI(z0,y0,x1), wx*(1-wy)*(1-wz));
      acc32(acc, gb + GI(z0,y1,x0), (1-wx)*wy*(1-wz));
      acc32(acc, gb + GI(z0,y1,x1), wx*wy*(1-wz));
      acc32(acc, gb + GI(z1,y0,x0), (1-wx)*(1-wy)*wz);
      acc32(acc, gb + GI(z1,y0,x1), wx*(1-wy)*wz);
      acc32(acc, gb + GI(z1,y1,x0), (1-wx)*wy*wz);
      acc32(acc, gb + GI(z1,y1,x1), wx*wy*wz);
    } else {
      float uu = (pl == 2) ? uy : ux;
      float vv = (pl == 1) ? uy : uz;
      float fx = uu * 127.f, fy = vv * 127.f;
      int x0 = (int)fx, y0 = (int)fy;
      float wx = fx - x0, wy = fy - y0;
      int x1 = min(x0 + 1, 127), y1 = min(y0 + 1, 127);
      const unsigned short* pb = ptab + ((size_t)((pl - 1) * BATCH + b) * 16384) * 32;
      acc32(acc, pb + ((size_t)(y0*128 + x0)) * 32, (1-wx)*(1-wy));
      acc32(acc, pb + ((size_t)(y0*128 + x1)) * 32, wx*(1-wy));
      acc32(acc, pb + ((size_t)(y1*128 + x0)) * 32, (1-wx)*wy);
      acc32(acc, pb + ((size_t)(y1*128 + x1)) * 32, wx*wy);
    }
    store32_lds(&act[(size_t)mloc * CF_STRIDE + pl * 32], acc);
  }
  __syncthreads();   // cf staging complete

  // ---- hoist cf B-fragments into persistent registers (identical for every wave) ----
  short8 cfB[4][4];   // [fn][ks]
#pragma unroll
  for (int fn = 0; fn < 4; fn++)
#pragma unroll
    for (int ks = 0; ks < 4; ks++)
      cfB[fn][ks] = *(const short8*)(&act[(size_t)(fn*16 + lr) * CF_STRIDE + ks*32 + lq*8]);

  floatx4 net[4][4];   // [fm][fn]; hidden = w*64 + fm*16 + lq*4 + r ; point = fn*16 + lr

  // ---- init: net = p @ Wp + bp ----
  float pv[4][3];
#pragma unroll
  for (int fn = 0; fn < 4; fn++) {
    int pg = ptile + fn * 16 + lr;
    pv[fn][0] = p[pg*3]; pv[fn][1] = p[pg*3+1]; pv[fn][2] = p[pg*3+2];
  }
#pragma unroll
  for (int fm = 0; fm < 4; fm++) {
    int h4 = w*16 + fm*4 + lq;
    float4 w0q = ((const float4*)Wp)[h4];
    float4 w1q = ((const float4*)(Wp + 256))[h4];
    float4 w2q = ((const float4*)(Wp + 512))[h4];
    float4 bq  = ((const float4*)bp)[h4];
    float wq[4][3] = {{w0q.x,w1q.x,w2q.x},{w0q.y,w1q.y,w2q.y},
                      {w0q.z,w1q.z,w2q.z},{w0q.w,w1q.w,w2q.w}};
    float bb[4] = {bq.x, bq.y, bq.z, bq.w};
#pragma unroll
    for (int r = 0; r < 4; r++)
#pragma unroll
      for (int fn = 0; fn < 4; fn++)
        net[fm][fn][r] = bb[r] + pv[fn][0]*wq[r][0] + pv[fn][1]*wq[r][1] + pv[fn][2]*wq[r][2];
  }
  __syncthreads();   // all staging reads done; act is free for the K-loop

  for (int i = 0; i < NBLK; i++) {
    // ---- S1: net += Wc^T . c^T  (K = 128, B-frags in registers) ----
    const unsigned short* wcb = wcp + i * 32768;
#pragma unroll
    for (int ks = 0; ks < 4; ks++) {
      short8 af[4];
#pragma unroll
      for (int fm = 0; fm < 4; fm++)
        af[fm] = *(const short8*)(wcb + (size_t)(ks*16 + w*4 + fm) * 512 + l*8);
#pragma unroll
      for (int fm = 0; fm < 4; fm++)
#pragma unroll
        for (int fn = 0; fn < 4; fn++)
          net[fm][fn] = __builtin_amdgcn_mfma_f32_16x16x32_bf16(af[fm], cfB[fn][ks], net[fm][fn], 0, 0, 0);
    }
    // ---- + bc, stage relu(net) -> act  (prev iter's S2 act-reads fenced by prev B2) ----
#pragma unroll
    for (int fm = 0; fm < 4; fm++) {
      float4 bq = ((const float4*)(bc + i*256))[w*16 + fm*4 + lq];
      float bb[4] = {bq.x, bq.y, bq.z, bq.w};
#pragma unroll
      for (int fn = 0; fn < 4; fn++) {
#pragma unroll
        for (int r = 0; r < 4; r++) net[fm][fn][r] += bb[r];
        uint2 uu;
        uu.x = pk2(fmaxf(net[fm][fn][0],0.f), fmaxf(net[fm][fn][1],0.f));
        uu.y = pk2(fmaxf(net[fm][fn][2],0.f), fmaxf(net[fm][fn][3],0.f));
        *(uint2*)(&act[(size_t)(fn*16 + lr) * ACT_STRIDE + w*64 + fm*16 + lq*4]) = uu;
      }
    }
    __syncthreads();   // B1: act complete; also fences last iter's act2 reads
    // ---- S2: h = W0^T . relu(net)^T  (K = 256), fmh-split; write relu(h) -> act2 ----
    const unsigned short* w0b = w0p + i * 65536;
#pragma unroll
    for (int fmh = 0; fmh < 2; fmh++) {
      floatx4 h[2][4];
#pragma unroll
      for (int fm2 = 0; fm2 < 2; fm2++)
#pragma unroll
        for (int fn = 0; fn < 4; fn++) h[fm2][fn] = (floatx4){0.f,0.f,0.f,0.f};
#pragma unroll
      for (int ks = 0; ks < 8; ks++) {
        short8 af[2], bf[4];
#pragma unroll
        for (int fm2 = 0; fm2 < 2; fm2++)
          af[fm2] = *(const short8*)(w0b + (size_t)(ks*16 + w*4 + fmh*2 + fm2) * 512 + l*8);
#pragma unroll
        for (int fn = 0; fn < 4; fn++)
          bf[fn] = *(const short8*)(&act[(size_t)(fn*16 + lr) * ACT_STRIDE + ks*32 + lq*8]);
#pragma unroll
        for (int fm2 = 0; fm2 < 2; fm2++)
#pragma unroll
          for (int fn = 0; fn < 4; fn++)
            h[fm2][fn] = __builtin_amdgcn_mfma_f32_16x16x32_bf16(af[fm2], bf[fn], h[fm2][fn], 0, 0, 0);
      }
#pragma unroll
      for (int fm2 = 0; fm2 < 2; fm2++) {
        int fmg = fmh*2 + fm2;
        float4 bq = ((const float4*)(b0 + i*256))[w*16 + fmg*4 + lq];
        float bb[4] = {bq.x, bq.y, bq.z, bq.w};
#pragma unroll
        for (int fn = 0; fn < 4; fn++) {
          uint2 uu;
          uu.x = pk2(fmaxf(h[fm2][fn][0]+bb[0],0.f), fmaxf(h[fm2][fn][1]+bb[1],0.f));
          uu.y = pk2(fmaxf(h[fm2][fn][2]+bb[2],0.f), fmaxf(h[fm2][fn][3]+bb[3],0.f));
          *(uint2*)(&act2[(size_t)(fn*16 + lr) * ACT_STRIDE + w*64 + fmg*16 + lq*4]) = uu;
        }
      }
    }
    __syncthreads();   // B2: act2 complete; also fences this iter's act reads
    // ---- S3: net += W1^T . relu(h)^T + b1 ----
    const unsigned short* w1b = w1p + i * 65536;
#pragma unroll
    for (int ks = 0; ks < 8; ks++) {
      short8 af[4], bf[4];
#pragma unroll
      for (int fm = 0; fm < 4; fm++)
        af[fm] = *(const short8*)(w1b + (size_t)(ks*16 + w*4 + fm) * 512 + l*8);
#pragma unroll
      for (int fn = 0; fn < 4; fn++)
        bf[fn] = *(const short8*)(&act2[(size_t)(fn*16 + lr) * ACT_STRIDE + ks*32 + lq*8]);
#pragma unroll
      for (int fm = 0; fm < 4; fm++)
#pragma unroll
        for (int fn = 0; fn < 4; fn++)
          net[fm][fn] = __builtin_amdgcn_mfma_f32_16x16x32_bf16(af[fm], bf[fn], net[fm][fn], 0, 0, 0);
    }
#pragma unroll
    for (int fm = 0; fm < 4; fm++) {
      float4 bq = ((const float4*)(b1 + i*256))[w*16 + fm*4 + lq];
      float bb[4] = {bq.x, bq.y, bq.z, bq.w};
#pragma unroll
      for (int r = 0; r < 4; r++)
#pragma unroll
        for (int fn = 0; fn < 4; fn++) net[fm][fn][r] += bb[r];
    }
  }

  // ---- out = relu(net) @ Wout + bout ----
  float s[4] = {0.f, 0.f, 0.f, 0.f};
#pragma unroll
  for (int fm = 0; fm < 4; fm++) {
    float4 wq = ((const float4*)Wout)[w*16 + fm*4 + lq];
    float wv[4] = {wq.x, wq.y, wq.z, wq.w};
#pragma unroll
    for (int r = 0; r < 4; r++)
#pragma unroll
      for (int fn = 0; fn < 4; fn++) s[fn] += fmaxf(net[fm][fn][r], 0.f) * wv[r];
  }
#pragma unroll
  for (int fn = 0; fn < 4; fn++) {
    s[fn] += __shfl_xor(s[fn], 16);
    s[fn] += __shfl_xor(s[fn], 32);
  }
  if (tid < 64) obuf[tid] = 0.f;
  __syncthreads();
  if (lq == 0) {
#pragma unroll
    for (int fn = 0; fn < 4; fn++) atomicAdd(&obuf[fn*16 + lr], s[fn]);
  }
  __syncthreads();
  if (tid < 64) out[ptile + tid] = obuf[tid] + bout[0];
}

extern "C" void kernel_launch(void* const* d_in, const int* in_sizes, int n_in,
                              void* d_out, int out_size, void* d_ws, size_t ws_size,
                              hipStream_t stream) {
  const float* p      = (const float*)d_in[0];
  const float* c_grid = (const float*)d_in[1];
  const float* c_xy   = (const float*)d_in[2];
  const float* c_yz   = (const float*)d_in[3];
  const float* c_xz   = (const float*)d_in[4];
  const float* Wp     = (const float*)d_in[5];
  const float* bp     = (const float*)d_in[6];
  const float* Wc     = (const float*)d_in[7];
  const float* bc     = (const float*)d_in[8];
  const float* W0     = (const float*)d_in[9];
  const float* b0     = (const float*)d_in[10];
  const float* W1     = (const float*)d_in[11];
  const float* b1     = (const float*)d_in[12];
  const float* Wout   = (const float*)d_in[13];
  const float* bout   = (const float*)d_in[14];

  char* ws = (char*)d_ws;
  unsigned short* wcp = (unsigned short*)(ws + OFF_WCP);
  unsigned short* w0p = (unsigned short*)(ws + OFF_W0P);
  unsigned short* w1p = (unsigned short*)(ws + OFF_W1P);
  unsigned short* gt  = (unsigned short*)(ws + OFF_GT);
  unsigned short* pt  = (unsigned short*)(ws + OFF_PT);
  float* out = (float*)d_out;

  prep<<<4480, 256, 0, stream>>>(Wc, W0, W1, c_grid, c_xy, c_yz, c_xz,
                                 wcp, w0p, w1p, gt, pt);
  mlp<<<MTOT / 64, 256, 0, stream>>>(p, Wp, bp, bc, b0, b1, Wout, bout,
                                     wcp, w0p, w1p, gt, pt, out);
}